// Round 4
// baseline (263.824 us; speedup 1.0000x reference)
//
#include <hip/hip_runtime.h>
#include <math.h>

#define BB 16384      // B
#define CC 50         // clusters
#define KK 128        // top-K
#define DD 128        // feature dim
#define MM 12800      // CC*2*KK rows of F
#define NSPLIT 20     // column splits for sim_all
#define CPS (MM / NSPLIT)       // 640 cols per split
#define TILE_COLS 32
#define TILES_PER_SPLIT (CPS / TILE_COLS)   // 20
#define SCALE2 2.8853900817779268f          // 2/ln2 : exp(x/0.5)=exp2(x*SCALE2)
#define MAXCAND 2048
#define TCAND 0.97f

// Tiled F layout (per hi/lo buffer): for each 16-row group g, each kc (32-K
// chunk), 64 granules of 16B stored lane-ordered: granule(lane) holds
// row = g*16 + (lane&15), bytes [kc*64 + (lane>>4)*16, +16) of that row.
// => an MFMA fragment load (A or B) for (group, kc) is ONE contiguous 1KB
// wave load at  base + g*4096 + kc*1024 + lane*16.  (16 groups per row-block)

typedef __bf16 bf16x8 __attribute__((ext_vector_type(8)));
typedef float f32x4 __attribute__((ext_vector_type(4)));

// ---------------- float <-> bf16 (RNE), self-contained ----------------
__device__ inline unsigned short f2bf(float x) {
  unsigned u = __float_as_uint(x);
  unsigned r = (u + 0x7fffu + ((u >> 16) & 1u)) >> 16;
  return (unsigned short)r;
}
__device__ inline float bf2f(unsigned short h) {
  return __uint_as_float(((unsigned)h) << 16);
}

// ---------------------------------------------------------------------------
// Kernel 1a: coalesced candidate collection (values >= TCAND).
// ---------------------------------------------------------------------------
__global__ void cand_kernel(const float* __restrict__ prob, int* __restrict__ candCnt,
                            int* __restrict__ candIdx, float* __restrict__ candVal) {
  const int n = blockIdx.x * 256 + threadIdx.x;
  if (n >= BB * CC) return;
  const float v = prob[n];
  if (v >= TCAND) {
    const int i = n / CC, c = n - i * CC;
    const int slot = atomicAdd(&candCnt[c], 1);
    if (slot < MAXCAND) {
      candIdx[c * MAXCAND + slot] = i;
      candVal[c * MAXCAND + slot] = v;
    }
  }
}

// ---------------------------------------------------------------------------
// Kernel 1b: per-cluster exact top-K (fast path in LDS; exact fallback).
// ---------------------------------------------------------------------------
__global__ void select_kernel(const float* __restrict__ prob,
                              const int* __restrict__ candCnt,
                              const int* __restrict__ candIdx,
                              const float* __restrict__ candVal,
                              int* __restrict__ topk) {
  __shared__ float vals[MAXCAND];
  __shared__ int   idxs[MAXCAND];
  __shared__ int hist[256];
  __shared__ int sChosen, sKrem, gtc, eqc;
  __shared__ int eqIdx[256];
  const int c = blockIdx.x, t = threadIdx.x;
  const int cnt = candCnt[c];

  if (cnt >= KK && cnt <= MAXCAND) {
    for (int j = t; j < cnt; j += 256) {
      vals[j] = candVal[c * MAXCAND + j];
      idxs[j] = candIdx[c * MAXCAND + j];
    }
    __syncthreads();
    unsigned prefix = 0;
    int krem = KK;
    for (int pass = 0; pass < 4; ++pass) {
      const int shift = 24 - pass * 8;
      hist[t] = 0;
      __syncthreads();
      for (int j = t; j < cnt; j += 256) {
        unsigned u = __float_as_uint(vals[j]);
        bool match = (pass == 0) || ((u >> (shift + 8)) == (prefix >> (shift + 8)));
        if (match) atomicAdd(&hist[(u >> shift) & 255], 1);
      }
      __syncthreads();
      if (t == 0) {
        int kr = krem, b = 255;
        for (; b > 0; --b) {
          if (kr > hist[b]) kr -= hist[b];
          else break;
        }
        sChosen = b; sKrem = kr;
      }
      __syncthreads();
      prefix |= ((unsigned)sChosen) << shift;
      krem = sKrem;
      __syncthreads();
    }
    const unsigned T = prefix;
    if (t == 0) { gtc = 0; eqc = 0; }
    __syncthreads();
    for (int j = t; j < cnt; j += 256) {
      unsigned u = __float_as_uint(vals[j]);
      if (u > T) {
        int pos = atomicAdd(&gtc, 1);
        topk[c * KK + pos] = idxs[j];
      } else if (u == T) {
        int e = atomicAdd(&eqc, 1);
        if (e < 256) eqIdx[e] = idxs[j];
      }
    }
    __syncthreads();
    if (t == 0) {
      int base = gtc;
      int ec = eqc < 256 ? eqc : 256;
      for (int j2 = 0; j2 < krem; ++j2) {
        int bi = -1, bv = 0x7fffffff;
        for (int q = 0; q < ec; ++q) {
          int v = eqIdx[q];
          if (v >= 0 && v < bv) { bv = v; bi = q; }
        }
        topk[c * KK + base + j2] = bv;
        eqIdx[bi] = -1;
      }
    }
  } else {
    // exact fallback: full strided column radix select
    unsigned prefix = 0;
    int krem = KK;
    for (int pass = 0; pass < 4; ++pass) {
      const int shift = 24 - pass * 8;
      hist[t] = 0;
      __syncthreads();
      for (int i = t; i < BB; i += 256) {
        unsigned u = __float_as_uint(prob[i * CC + c]);
        bool match = (pass == 0) || ((u >> (shift + 8)) == (prefix >> (shift + 8)));
        if (match) atomicAdd(&hist[(u >> shift) & 255], 1);
      }
      __syncthreads();
      if (t == 0) {
        int kr = krem, b = 255;
        for (; b > 0; --b) {
          if (kr > hist[b]) kr -= hist[b];
          else break;
        }
        sChosen = b; sKrem = kr;
      }
      __syncthreads();
      prefix |= ((unsigned)sChosen) << shift;
      krem = sKrem;
      __syncthreads();
    }
    const unsigned T = prefix;
    if (t == 0) { gtc = 0; eqc = 0; }
    __syncthreads();
    for (int i = t; i < BB; i += 256) {
      unsigned u = __float_as_uint(prob[i * CC + c]);
      if (u > T) {
        int pos = atomicAdd(&gtc, 1);
        topk[c * KK + pos] = i;
      } else if (u == T) {
        int e = atomicAdd(&eqc, 1);
        if (e < 256) eqIdx[e] = i;
      }
    }
    __syncthreads();
    if (t == 0) {
      int base = gtc;
      int ec = eqc < 256 ? eqc : 256;
      for (int j = 0; j < krem; ++j) {
        int bi = -1, bv = 0x7fffffff;
        for (int q = 0; q < ec; ++q) {
          int v = eqIdx[q];
          if (v >= 0 && v < bv) { bv = v; bi = q; }
        }
        topk[c * KK + base + j] = bv;
        eqIdx[bi] = -1;
      }
    }
  }
}

// ---------------------------------------------------------------------------
// Kernel 2: gather + L2-normalize + hi/lo bf16 split, written TILED.
// One wave per row. Lane holds feature pair k = {2*lane, 2*lane+1}.
// Tiled dest: g=row>>4, kc=lane>>4, quarter=(lane>>2)&3, byte=(lane&3)*4.
// ---------------------------------------------------------------------------
__global__ void gather_norm(const float* __restrict__ zi, const float* __restrict__ zj,
                            const int* __restrict__ topk,
                            char* __restrict__ FhiT, char* __restrict__ FloT) {
  const int gw = (blockIdx.x * 256 + threadIdx.x) >> 6;
  const int lane = threadIdx.x & 63;
  if (gw >= MM) return;
  const int c = gw >> 8, p = gw & 255;
  const int idx = topk[c * KK + (p & (KK - 1))];
  const float* src = (p < KK ? zi : zj) + (size_t)idx * DD;
  float2 v = ((const float2*)src)[lane];
  float ss = fmaf(v.x, v.x, v.y * v.y);
#pragma unroll
  for (int m = 1; m < 64; m <<= 1) ss += __shfl_xor(ss, m, 64);
  const float scale = 1.0f / fmaxf(sqrtf(ss), 1e-8f);
  float a = v.x * scale, b = v.y * scale;
  unsigned short ah = f2bf(a), bh = f2bf(b);
  unsigned short al = f2bf(a - bf2f(ah)), bl = f2bf(b - bf2f(bh));
  unsigned hp = ((unsigned)bh << 16) | ah;
  unsigned lp = ((unsigned)bl << 16) | al;
  const size_t off = (size_t)(gw >> 4) * 4096 + (size_t)(lane >> 4) * 1024 +
                     (size_t)((((lane >> 2) & 3) * 16 + (gw & 15)) * 16 + (lane & 3) * 4);
  *(unsigned*)(FhiT + off) = hp;
  *(unsigned*)(FloT + off) = lp;
}

// ---------------------------------------------------------------------------
// Kernel 3: sum_all — LDS-FREE. Block = 4 waves x 64 rows (one cluster),
// cols = one split (640) in 32-col tiles. A (hi+lo) resident in registers;
// B fragments streamed straight from global (L1/L2-resident, 1KB coalesced
// loads). acc is per-(tile,cg) -> only 16 acc VGPRs live.
// ---------------------------------------------------------------------------
__global__ __launch_bounds__(256, 2) void sim_all_kernel(
    const char* __restrict__ FhiT, const char* __restrict__ FloT,
    float* __restrict__ part) {
  const int tid = threadIdx.x;
  const int lane = tid & 63, wave = tid >> 6;
  const int c = blockIdx.x / NSPLIT, split = blockIdx.x - c * NSPLIT;
  const int rowW = c * 256 + wave * 64;
  const int lh = lane >> 4;
  const size_t laneoff = (size_t)lane * 16;

  // A fragments: 64 rows = groups (rowW>>4)+0..3
  bf16x8 Ahi[4][4], Alo[4][4];
#pragma unroll
  for (int rg = 0; rg < 4; ++rg)
#pragma unroll
    for (int kc = 0; kc < 4; ++kc) {
      const size_t off = (size_t)((rowW >> 4) + rg) * 4096 + (size_t)kc * 1024 + laneoff;
      Ahi[rg][kc] = *(const bf16x8*)(FhiT + off);
      Alo[rg][kc] = *(const bf16x8*)(FloT + off);
    }

  float sAll[16] = {0.f};
  const int cg0 = (split * CPS) >> 4;   // starting 16-col group

  for (int t = 0; t < TILES_PER_SPLIT; ++t) {
#pragma unroll
    for (int cg = 0; cg < 2; ++cg) {
      const size_t gb = (size_t)(cg0 + t * 2 + cg) * 4096 + laneoff;
      bf16x8 bh[4], bl[4];
#pragma unroll
      for (int kc = 0; kc < 4; ++kc) {
        bh[kc] = *(const bf16x8*)(FhiT + gb + kc * 1024);
        bl[kc] = *(const bf16x8*)(FloT + gb + kc * 1024);
      }
      f32x4 acc[4] = {};
#pragma unroll
      for (int kc = 0; kc < 4; ++kc) {
#pragma unroll
        for (int rg = 0; rg < 4; ++rg)
          acc[rg] = __builtin_amdgcn_mfma_f32_16x16x32_bf16(Ahi[rg][kc], bh[kc], acc[rg], 0, 0, 0);
#pragma unroll
        for (int rg = 0; rg < 4; ++rg)
          acc[rg] = __builtin_amdgcn_mfma_f32_16x16x32_bf16(Ahi[rg][kc], bl[kc], acc[rg], 0, 0, 0);
#pragma unroll
        for (int rg = 0; rg < 4; ++rg)
          acc[rg] = __builtin_amdgcn_mfma_f32_16x16x32_bf16(Alo[rg][kc], bh[kc], acc[rg], 0, 0, 0);
      }
#pragma unroll
      for (int rg = 0; rg < 4; ++rg)
#pragma unroll
        for (int i = 0; i < 4; ++i)
          sAll[rg * 4 + i] += __builtin_amdgcn_exp2f(acc[rg][i] * SCALE2);
    }
  }

  // reduce across the 16 column-lanes
#pragma unroll
  for (int m = 1; m < 16; m <<= 1)
#pragma unroll
    for (int j = 0; j < 16; ++j) sAll[j] += __shfl_xor(sAll[j], m, 16);
  if ((lane & 15) == 0) {
#pragma unroll
    for (int rg = 0; rg < 4; ++rg)
#pragma unroll
      for (int i = 0; i < 4; ++i) {
        int row = rowW + rg * 16 + lh * 4 + i;
        part[(size_t)row * NSPLIT + split] = sAll[rg * 4 + i];
      }
  }
}

// ---------------------------------------------------------------------------
// Kernel 4: own-block sums — LDS-FREE, same tiled reads. 200 blocks;
// wave owns 16 rows; cols = the cluster's 256 in 8 tiles.
// ---------------------------------------------------------------------------
__global__ __launch_bounds__(256) void own_kernel(
    const char* __restrict__ FhiT, const char* __restrict__ FloT,
    float* __restrict__ ownArr, float* __restrict__ posArr) {
  const int tid = threadIdx.x;
  const int lane = tid & 63, wave = tid >> 6;
  const int c = blockIdx.x >> 2, q = blockIdx.x & 3;
  const int rowW = c * 256 + q * 64 + wave * 16;
  const int lh = lane >> 4;
  const size_t laneoff = (size_t)lane * 16;

  bf16x8 Ahi[4], Alo[4];
#pragma unroll
  for (int kc = 0; kc < 4; ++kc) {
    const size_t off = (size_t)(rowW >> 4) * 4096 + (size_t)kc * 1024 + laneoff;
    Ahi[kc] = *(const bf16x8*)(FhiT + off);
    Alo[kc] = *(const bf16x8*)(FloT + off);
  }

  float sOwn[4] = {0.f}, sPos[4] = {0.f};
  const int cg0 = c * 16;

  for (int t = 0; t < 8; ++t) {
    float e[4] = {0.f, 0.f, 0.f, 0.f};
#pragma unroll
    for (int cg = 0; cg < 2; ++cg) {
      const size_t gb = (size_t)(cg0 + t * 2 + cg) * 4096 + laneoff;
      bf16x8 bh[4], bl[4];
#pragma unroll
      for (int kc = 0; kc < 4; ++kc) {
        bh[kc] = *(const bf16x8*)(FhiT + gb + kc * 1024);
        bl[kc] = *(const bf16x8*)(FloT + gb + kc * 1024);
      }
      f32x4 acc = {};
#pragma unroll
      for (int kc = 0; kc < 4; ++kc) {
        acc = __builtin_amdgcn_mfma_f32_16x16x32_bf16(Ahi[kc], bh[kc], acc, 0, 0, 0);
        acc = __builtin_amdgcn_mfma_f32_16x16x32_bf16(Ahi[kc], bl[kc], acc, 0, 0, 0);
        acc = __builtin_amdgcn_mfma_f32_16x16x32_bf16(Alo[kc], bh[kc], acc, 0, 0, 0);
      }
#pragma unroll
      for (int i = 0; i < 4; ++i) e[i] += __builtin_amdgcn_exp2f(acc[i] * SCALE2);
    }
    const bool isPos = (t < 4);
#pragma unroll
    for (int i = 0; i < 4; ++i) {
      sOwn[i] += e[i];
      if (isPos) sPos[i] += e[i];
    }
  }
#pragma unroll
  for (int m = 1; m < 16; m <<= 1)
#pragma unroll
    for (int i = 0; i < 4; ++i) {
      sOwn[i] += __shfl_xor(sOwn[i], m, 16);
      sPos[i] += __shfl_xor(sPos[i], m, 16);
    }
  if ((lane & 15) == 0) {
#pragma unroll
    for (int i = 0; i < 4; ++i) {
      int row = rowW + lh * 4 + i;
      ownArr[row] = sOwn[i];
      posArr[row] = sPos[i];
    }
  }
}

// ---------------------------------------------------------------------------
// Kernel 5: per-row loss
// ---------------------------------------------------------------------------
__global__ void finalize_rows(const float* __restrict__ part,
                              const float* __restrict__ ownArr,
                              const float* __restrict__ posArr,
                              float* __restrict__ row_loss) {
  const int p = blockIdx.x * 256 + threadIdx.x;
  if (p >= MM) return;
  float a = 0.f;
#pragma unroll
  for (int sp = 0; sp < NSPLIT; ++sp) a += part[(size_t)p * NSPLIT + sp];
  row_loss[p] = logf(a - ownArr[p]) - logf(posArr[p]);
}

// ---------------------------------------------------------------------------
// Kernel 6: mean -> scalar
// ---------------------------------------------------------------------------
__global__ void final_reduce(const float* __restrict__ row_loss, float* __restrict__ out) {
  __shared__ float red[16];
  const int t = threadIdx.x;                // 1024 threads
  float ssum = 0.f;
  for (int i = t; i < MM; i += 1024) ssum += row_loss[i];
#pragma unroll
  for (int m = 1; m < 64; m <<= 1) ssum += __shfl_xor(ssum, m, 64);
  if ((t & 63) == 0) red[t >> 6] = ssum;
  __syncthreads();
  if (t < 16) {
    float v = red[t];
#pragma unroll
    for (int m = 1; m < 16; m <<= 1) v += __shfl_xor(v, m, 16);
    if (t == 0) out[0] = v * (1.0f / MM);
  }
}

extern "C" void kernel_launch(void* const* d_in, const int* in_sizes, int n_in,
                              void* d_out, int out_size, void* d_ws, size_t ws_size,
                              hipStream_t stream) {
  const float* prob = (const float*)d_in[0];
  const float* zi   = (const float*)d_in[1];
  const float* zj   = (const float*)d_in[2];
  float* out = (float*)d_out;

  char* ws = (char*)d_ws;
  char* FhiT      = ws;                                              // 3,276,800 B
  char* FloT      = ws + 3276800;                                    // 3,276,800 B
  float* part     = (float*)(ws + 6553600);                          // 1,024,000 B
  float* ownArr   = (float*)(ws + 7577600);                          //    51,200 B
  float* posArr   = (float*)(ws + 7628800);                          //    51,200 B
  float* row_loss = (float*)(ws + 7680000);                          //    51,200 B
  int*   topk     = (int*)  (ws + 7731200);                          //    25,600 B
  int*   candCnt  = (int*)  (ws + 7756800);                          //       256 B
  int*   candIdx  = (int*)  (ws + 7757056);                          //   409,600 B
  float* candVal  = (float*)(ws + 8166656);                          //   409,600 B

  hipMemsetAsync(candCnt, 0, 256, stream);
  cand_kernel   <<<(BB * CC + 255) / 256, 256, 0, stream>>>(prob, candCnt, candIdx, candVal);
  select_kernel <<<CC, 256, 0, stream>>>(prob, candCnt, candIdx, candVal, topk);
  gather_norm   <<<MM / 4, 256, 0, stream>>>(zi, zj, topk, FhiT, FloT);
  sim_all_kernel<<<CC * NSPLIT, 256, 0, stream>>>(FhiT, FloT, part);
  own_kernel    <<<CC * 4, 256, 0, stream>>>(FhiT, FloT, ownArr, posArr);
  finalize_rows <<<MM / 256, 256, 0, stream>>>(part, ownArr, posArr, row_loss);
  final_reduce  <<<1, 1024, 0, stream>>>(row_loss, out);
}

// Round 5
// 246.186 us; speedup vs baseline: 1.0716x; 1.0716x over previous
//
#include <hip/hip_runtime.h>
#include <math.h>

#define BB 16384      // B
#define CC 50         // clusters
#define KK 128        // top-K
#define DD 128        // feature dim
#define MM 12800      // CC*2*KK rows of F
#define NSPLIT 20     // column splits for sim_all
#define CPS (MM / NSPLIT)       // 640 cols per split
#define CGS_PER_SPLIT (CPS / 16)            // 40 column groups of 16
#define SCALE2 2.8853900817779268f          // 2/ln2 : exp(x/0.5)=exp2(x*SCALE2)
#define MAXCAND 2048
#define TCAND 0.97f

// Tiled F layout (per hi/lo buffer): for each 16-row group g, each kc (32-K
// chunk), 64 granules of 16B stored lane-ordered: granule(lane) holds
// row = g*16 + (lane&15), bytes [kc*64 + (lane>>4)*16, +16) of that row.
// => an MFMA fragment load (A or B) for (group, kc) is ONE contiguous 1KB
// wave load at  base + g*4096 + kc*1024 + lane*16.

typedef __bf16 bf16x8 __attribute__((ext_vector_type(8)));
typedef float f32x4 __attribute__((ext_vector_type(4)));

__device__ inline unsigned short f2bf(float x) {
  unsigned u = __float_as_uint(x);
  unsigned r = (u + 0x7fffu + ((u >> 16) & 1u)) >> 16;
  return (unsigned short)r;
}
__device__ inline float bf2f(unsigned short h) {
  return __uint_as_float(((unsigned)h) << 16);
}

// ---------------------------------------------------------------------------
// Kernel 1a: coalesced candidate collection (values >= TCAND).
// ---------------------------------------------------------------------------
__global__ void cand_kernel(const float* __restrict__ prob, int* __restrict__ candCnt,
                            int* __restrict__ candIdx, float* __restrict__ candVal) {
  const int n = blockIdx.x * 256 + threadIdx.x;
  if (n >= BB * CC) return;
  const float v = prob[n];
  if (v >= TCAND) {
    const int i = n / CC, c = n - i * CC;
    const int slot = atomicAdd(&candCnt[c], 1);
    if (slot < MAXCAND) {
      candIdx[c * MAXCAND + slot] = i;
      candVal[c * MAXCAND + slot] = v;
    }
  }
}

// ---------------------------------------------------------------------------
// Kernel 1b: per-cluster exact top-K (fast path in LDS; exact fallback).
// ---------------------------------------------------------------------------
__global__ void select_kernel(const float* __restrict__ prob,
                              const int* __restrict__ candCnt,
                              const int* __restrict__ candIdx,
                              const float* __restrict__ candVal,
                              int* __restrict__ topk) {
  __shared__ float vals[MAXCAND];
  __shared__ int   idxs[MAXCAND];
  __shared__ int hist[256];
  __shared__ int sChosen, sKrem, gtc, eqc;
  __shared__ int eqIdx[256];
  const int c = blockIdx.x, t = threadIdx.x;
  const int cnt = candCnt[c];

  if (cnt >= KK && cnt <= MAXCAND) {
    for (int j = t; j < cnt; j += 256) {
      vals[j] = candVal[c * MAXCAND + j];
      idxs[j] = candIdx[c * MAXCAND + j];
    }
    __syncthreads();
    unsigned prefix = 0;
    int krem = KK;
    for (int pass = 0; pass < 4; ++pass) {
      const int shift = 24 - pass * 8;
      hist[t] = 0;
      __syncthreads();
      for (int j = t; j < cnt; j += 256) {
        unsigned u = __float_as_uint(vals[j]);
        bool match = (pass == 0) || ((u >> (shift + 8)) == (prefix >> (shift + 8)));
        if (match) atomicAdd(&hist[(u >> shift) & 255], 1);
      }
      __syncthreads();
      if (t == 0) {
        int kr = krem, b = 255;
        for (; b > 0; --b) {
          if (kr > hist[b]) kr -= hist[b];
          else break;
        }
        sChosen = b; sKrem = kr;
      }
      __syncthreads();
      prefix |= ((unsigned)sChosen) << shift;
      krem = sKrem;
      __syncthreads();
    }
    const unsigned T = prefix;
    if (t == 0) { gtc = 0; eqc = 0; }
    __syncthreads();
    for (int j = t; j < cnt; j += 256) {
      unsigned u = __float_as_uint(vals[j]);
      if (u > T) {
        int pos = atomicAdd(&gtc, 1);
        topk[c * KK + pos] = idxs[j];
      } else if (u == T) {
        int e = atomicAdd(&eqc, 1);
        if (e < 256) eqIdx[e] = idxs[j];
      }
    }
    __syncthreads();
    if (t == 0) {
      int base = gtc;
      int ec = eqc < 256 ? eqc : 256;
      for (int j2 = 0; j2 < krem; ++j2) {
        int bi = -1, bv = 0x7fffffff;
        for (int q = 0; q < ec; ++q) {
          int v = eqIdx[q];
          if (v >= 0 && v < bv) { bv = v; bi = q; }
        }
        topk[c * KK + base + j2] = bv;
        eqIdx[bi] = -1;
      }
    }
  } else {
    unsigned prefix = 0;
    int krem = KK;
    for (int pass = 0; pass < 4; ++pass) {
      const int shift = 24 - pass * 8;
      hist[t] = 0;
      __syncthreads();
      for (int i = t; i < BB; i += 256) {
        unsigned u = __float_as_uint(prob[i * CC + c]);
        bool match = (pass == 0) || ((u >> (shift + 8)) == (prefix >> (shift + 8)));
        if (match) atomicAdd(&hist[(u >> shift) & 255], 1);
      }
      __syncthreads();
      if (t == 0) {
        int kr = krem, b = 255;
        for (; b > 0; --b) {
          if (kr > hist[b]) kr -= hist[b];
          else break;
        }
        sChosen = b; sKrem = kr;
      }
      __syncthreads();
      prefix |= ((unsigned)sChosen) << shift;
      krem = sKrem;
      __syncthreads();
    }
    const unsigned T = prefix;
    if (t == 0) { gtc = 0; eqc = 0; }
    __syncthreads();
    for (int i = t; i < BB; i += 256) {
      unsigned u = __float_as_uint(prob[i * CC + c]);
      if (u > T) {
        int pos = atomicAdd(&gtc, 1);
        topk[c * KK + pos] = i;
      } else if (u == T) {
        int e = atomicAdd(&eqc, 1);
        if (e < 256) eqIdx[e] = i;
      }
    }
    __syncthreads();
    if (t == 0) {
      int base = gtc;
      int ec = eqc < 256 ? eqc : 256;
      for (int j = 0; j < krem; ++j) {
        int bi = -1, bv = 0x7fffffff;
        for (int q = 0; q < ec; ++q) {
          int v = eqIdx[q];
          if (v >= 0 && v < bv) { bv = v; bi = q; }
        }
        topk[c * KK + base + j] = bv;
        eqIdx[bi] = -1;
      }
    }
  }
}

// ---------------------------------------------------------------------------
// Kernel 2: gather + L2-normalize + hi/lo bf16 split, written TILED.
// ---------------------------------------------------------------------------
__global__ void gather_norm(const float* __restrict__ zi, const float* __restrict__ zj,
                            const int* __restrict__ topk,
                            char* __restrict__ FhiT, char* __restrict__ FloT) {
  const int gw = (blockIdx.x * 256 + threadIdx.x) >> 6;
  const int lane = threadIdx.x & 63;
  if (gw >= MM) return;
  const int c = gw >> 8, p = gw & 255;
  const int idx = topk[c * KK + (p & (KK - 1))];
  const float* src = (p < KK ? zi : zj) + (size_t)idx * DD;
  float2 v = ((const float2*)src)[lane];
  float ss = fmaf(v.x, v.x, v.y * v.y);
#pragma unroll
  for (int m = 1; m < 64; m <<= 1) ss += __shfl_xor(ss, m, 64);
  const float scale = 1.0f / fmaxf(sqrtf(ss), 1e-8f);
  float a = v.x * scale, b = v.y * scale;
  unsigned short ah = f2bf(a), bh = f2bf(b);
  unsigned short al = f2bf(a - bf2f(ah)), bl = f2bf(b - bf2f(bh));
  unsigned hp = ((unsigned)bh << 16) | ah;
  unsigned lp = ((unsigned)bl << 16) | al;
  const size_t off = (size_t)(gw >> 4) * 4096 + (size_t)(lane >> 4) * 1024 +
                     (size_t)((((lane >> 2) & 3) * 16 + (gw & 15)) * 16 + (lane & 3) * 4);
  *(unsigned*)(FhiT + off) = hp;
  *(unsigned*)(FloT + off) = lp;
}

// ---------------------------------------------------------------------------
// Kernel 3: fused sim. Blocks [0, CC*NSPLIT): sum_all with acc PING-PONG —
// while MFMAs fill acc_cur (col-group i), exp2-sum of acc_prev (group i-1)
// issues on the VALU/TRANS pipes, and B loads for group i+1 are in flight.
// Blocks [CC*NSPLIT, +CC*4): own/pos block sums (light path).
// ---------------------------------------------------------------------------
__global__ __launch_bounds__(256, 2) void sim_fused_kernel(
    const char* __restrict__ FhiT, const char* __restrict__ FloT,
    float* __restrict__ part, float* __restrict__ ownArr, float* __restrict__ posArr) {
  const int tid = threadIdx.x;
  const int lane = tid & 63, wave = tid >> 6;
  const int lh = lane >> 4;
  const size_t laneoff = (size_t)lane * 16;

  if (blockIdx.x < CC * NSPLIT) {
    // ================= sum_all path =================
    const int c = blockIdx.x / NSPLIT, split = blockIdx.x - c * NSPLIT;
    const int rowW = c * 256 + wave * 64;
    const int cgBase = (split * CPS) >> 4;

    bf16x8 Ahi[4][4], Alo[4][4];
#pragma unroll
    for (int rg = 0; rg < 4; ++rg)
#pragma unroll
      for (int kc = 0; kc < 4; ++kc) {
        const size_t off = (size_t)((rowW >> 4) + rg) * 4096 + (size_t)kc * 1024 + laneoff;
        Ahi[rg][kc] = *(const bf16x8*)(FhiT + off);
        Alo[rg][kc] = *(const bf16x8*)(FloT + off);
      }

    bf16x8 bh[4], bl[4];
    f32x4 acc0[4], acc1[4];
    float sAll[16] = {0.f};

#define LOADB(IDX) do {                                                        \
      const size_t gb = (size_t)(cgBase + (IDX)) * 4096 + laneoff;             \
      _Pragma("unroll")                                                        \
      for (int kc = 0; kc < 4; ++kc) {                                         \
        bh[kc] = *(const bf16x8*)(FhiT + gb + kc * 1024);                      \
        bl[kc] = *(const bf16x8*)(FloT + gb + kc * 1024);                      \
      }                                                                        \
    } while (0)

#define MFMAB(ACC) do {                                                        \
      _Pragma("unroll")                                                        \
      for (int rg = 0; rg < 4; ++rg)                                           \
        ACC[rg] = __builtin_amdgcn_mfma_f32_16x16x32_bf16(                     \
            Ahi[rg][0], bh[0], (f32x4){0.f, 0.f, 0.f, 0.f}, 0, 0, 0);          \
      _Pragma("unroll")                                                        \
      for (int rg = 0; rg < 4; ++rg)                                           \
        ACC[rg] = __builtin_amdgcn_mfma_f32_16x16x32_bf16(Ahi[rg][0], bl[0], ACC[rg], 0, 0, 0); \
      _Pragma("unroll")                                                        \
      for (int rg = 0; rg < 4; ++rg)                                           \
        ACC[rg] = __builtin_amdgcn_mfma_f32_16x16x32_bf16(Alo[rg][0], bh[0], ACC[rg], 0, 0, 0); \
      _Pragma("unroll")                                                        \
      for (int kc = 1; kc < 4; ++kc) {                                         \
        _Pragma("unroll")                                                      \
        for (int rg = 0; rg < 4; ++rg)                                         \
          ACC[rg] = __builtin_amdgcn_mfma_f32_16x16x32_bf16(Ahi[rg][kc], bh[kc], ACC[rg], 0, 0, 0); \
        _Pragma("unroll")                                                      \
        for (int rg = 0; rg < 4; ++rg)                                         \
          ACC[rg] = __builtin_amdgcn_mfma_f32_16x16x32_bf16(Ahi[rg][kc], bl[kc], ACC[rg], 0, 0, 0); \
        _Pragma("unroll")                                                      \
        for (int rg = 0; rg < 4; ++rg)                                         \
          ACC[rg] = __builtin_amdgcn_mfma_f32_16x16x32_bf16(Alo[rg][kc], bh[kc], ACC[rg], 0, 0, 0); \
      }                                                                        \
    } while (0)

#define EXPSUM(ACC) do {                                                       \
      _Pragma("unroll")                                                        \
      for (int rg = 0; rg < 4; ++rg)                                           \
        _Pragma("unroll")                                                      \
        for (int q = 0; q < 4; ++q)                                            \
          sAll[rg * 4 + q] += __builtin_amdgcn_exp2f(ACC[rg][q] * SCALE2);     \
    } while (0)

    // software pipeline: MFMA(cur) | prefetch(next) | exp(prev)
    LOADB(0);
    MFMAB(acc0);
    LOADB(1);
    for (int i = 1; i < CGS_PER_SPLIT - 1; i += 2) {
      MFMAB(acc1);
      LOADB(i + 1);
      EXPSUM(acc0);
      MFMAB(acc0);
      LOADB(i + 2);
      EXPSUM(acc1);
    }
    MFMAB(acc1);
    EXPSUM(acc0);
    EXPSUM(acc1);

#undef LOADB
#undef MFMAB
#undef EXPSUM

#pragma unroll
    for (int m = 1; m < 16; m <<= 1)
#pragma unroll
      for (int j = 0; j < 16; ++j) sAll[j] += __shfl_xor(sAll[j], m, 16);
    if ((lane & 15) == 0) {
#pragma unroll
      for (int rg = 0; rg < 4; ++rg)
#pragma unroll
        for (int i = 0; i < 4; ++i) {
          int row = rowW + rg * 16 + lh * 4 + i;
          part[(size_t)row * NSPLIT + split] = sAll[rg * 4 + i];
        }
    }
  } else {
    // ================= own/pos path =================
    const int bid2 = blockIdx.x - CC * NSPLIT;
    const int c = bid2 >> 2, q = bid2 & 3;
    const int rowW = c * 256 + q * 64 + wave * 16;
    const int cg0 = c * 16;

    bf16x8 Ahi[4], Alo[4];
#pragma unroll
    for (int kc = 0; kc < 4; ++kc) {
      const size_t off = (size_t)(rowW >> 4) * 4096 + (size_t)kc * 1024 + laneoff;
      Ahi[kc] = *(const bf16x8*)(FhiT + off);
      Alo[kc] = *(const bf16x8*)(FloT + off);
    }

    float sOwn[4] = {0.f}, sPos[4] = {0.f};
    for (int t = 0; t < 16; ++t) {
      const size_t gb = (size_t)(cg0 + t) * 4096 + laneoff;
      bf16x8 bh[4], bl[4];
#pragma unroll
      for (int kc = 0; kc < 4; ++kc) {
        bh[kc] = *(const bf16x8*)(FhiT + gb + kc * 1024);
        bl[kc] = *(const bf16x8*)(FloT + gb + kc * 1024);
      }
      f32x4 acc = {};
#pragma unroll
      for (int kc = 0; kc < 4; ++kc) {
        acc = __builtin_amdgcn_mfma_f32_16x16x32_bf16(Ahi[kc], bh[kc], acc, 0, 0, 0);
        acc = __builtin_amdgcn_mfma_f32_16x16x32_bf16(Ahi[kc], bl[kc], acc, 0, 0, 0);
        acc = __builtin_amdgcn_mfma_f32_16x16x32_bf16(Alo[kc], bh[kc], acc, 0, 0, 0);
      }
      const bool isPos = (t < 8);
#pragma unroll
      for (int i = 0; i < 4; ++i) {
        float e = __builtin_amdgcn_exp2f(acc[i] * SCALE2);
        sOwn[i] += e;
        if (isPos) sPos[i] += e;
      }
    }
#pragma unroll
    for (int m = 1; m < 16; m <<= 1)
#pragma unroll
      for (int i = 0; i < 4; ++i) {
        sOwn[i] += __shfl_xor(sOwn[i], m, 16);
        sPos[i] += __shfl_xor(sPos[i], m, 16);
      }
    if ((lane & 15) == 0) {
#pragma unroll
      for (int i = 0; i < 4; ++i) {
        int row = rowW + lh * 4 + i;
        ownArr[row] = sOwn[i];
        posArr[row] = sPos[i];
      }
    }
  }
}

// ---------------------------------------------------------------------------
// Kernel 4: per-row loss
// ---------------------------------------------------------------------------
__global__ void finalize_rows(const float* __restrict__ part,
                              const float* __restrict__ ownArr,
                              const float* __restrict__ posArr,
                              float* __restrict__ row_loss) {
  const int p = blockIdx.x * 256 + threadIdx.x;
  if (p >= MM) return;
  float a = 0.f;
#pragma unroll
  for (int sp = 0; sp < NSPLIT; ++sp) a += part[(size_t)p * NSPLIT + sp];
  row_loss[p] = logf(a - ownArr[p]) - logf(posArr[p]);
}

// ---------------------------------------------------------------------------
// Kernel 5: mean -> scalar
// ---------------------------------------------------------------------------
__global__ void final_reduce(const float* __restrict__ row_loss, float* __restrict__ out) {
  __shared__ float red[16];
  const int t = threadIdx.x;                // 1024 threads
  float ssum = 0.f;
  for (int i = t; i < MM; i += 1024) ssum += row_loss[i];
#pragma unroll
  for (int m = 1; m < 64; m <<= 1) ssum += __shfl_xor(ssum, m, 64);
  if ((t & 63) == 0) red[t >> 6] = ssum;
  __syncthreads();
  if (t < 16) {
    float v = red[t];
#pragma unroll
    for (int m = 1; m < 16; m <<= 1) v += __shfl_xor(v, m, 16);
    if (t == 0) out[0] = v * (1.0f / MM);
  }
}

extern "C" void kernel_launch(void* const* d_in, const int* in_sizes, int n_in,
                              void* d_out, int out_size, void* d_ws, size_t ws_size,
                              hipStream_t stream) {
  const float* prob = (const float*)d_in[0];
  const float* zi   = (const float*)d_in[1];
  const float* zj   = (const float*)d_in[2];
  float* out = (float*)d_out;

  char* ws = (char*)d_ws;
  char* FhiT      = ws;                                              // 3,276,800 B
  char* FloT      = ws + 3276800;                                    // 3,276,800 B
  float* part     = (float*)(ws + 6553600);                          // 1,024,000 B
  float* ownArr   = (float*)(ws + 7577600);                          //    51,200 B
  float* posArr   = (float*)(ws + 7628800);                          //    51,200 B
  float* row_loss = (float*)(ws + 7680000);                          //    51,200 B
  int*   topk     = (int*)  (ws + 7731200);                          //    25,600 B
  int*   candCnt  = (int*)  (ws + 7756800);                          //       256 B
  int*   candIdx  = (int*)  (ws + 7757056);                          //   409,600 B
  float* candVal  = (float*)(ws + 8166656);                          //   409,600 B

  hipMemsetAsync(candCnt, 0, 256, stream);
  cand_kernel     <<<(BB * CC + 255) / 256, 256, 0, stream>>>(prob, candCnt, candIdx, candVal);
  select_kernel   <<<CC, 256, 0, stream>>>(prob, candCnt, candIdx, candVal, topk);
  gather_norm     <<<MM / 4, 256, 0, stream>>>(zi, zj, topk, FhiT, FloT);
  sim_fused_kernel<<<CC * NSPLIT + CC * 4, 256, 0, stream>>>(FhiT, FloT, part, ownArr, posArr);
  finalize_rows   <<<MM / 256, 256, 0, stream>>>(part, ownArr, posArr, row_loss);
  final_reduce    <<<1, 1024, 0, stream>>>(row_loss, out);
}